// Round 2
// baseline (2159.965 us; speedup 1.0000x reference)
//
#include <hip/hip_runtime.h>
#include <cstdint>
#include <cstddef>

typedef _Float16 f16;
typedef _Float16 f16x8 __attribute__((ext_vector_type(8)));
typedef float f32x4 __attribute__((ext_vector_type(4)));

#define DEVI __device__ __forceinline__

// ---------------- problem sizes ----------------
constexpr int T_ = 256;
constexpr int BATCH = 512;
constexpr int M_ = BATCH * T_;   // 131072 tokens
constexpr int KE_ = 320;         // layer-1 K (300 padded to 320)
constexpr int K2_ = 256;         // layer-2 K

// ---------------- fixed ws region (bytes, all 16B aligned) ----------------
constexpr size_t OFF_EMB16 = 0;                                     // [10000][320] f16
constexpr size_t OFF_WIH1  = OFF_EMB16 + (size_t)10000 * KE_ * 2;   // [1024][320] f16 (row-permuted)
constexpr size_t OFF_WIH2  = OFF_WIH1 + (size_t)1024 * KE_ * 2;     // [1024][256] f16
constexpr size_t OFF_WHH   = OFF_WIH2 + (size_t)1024 * K2_ * 2;     // [4 ld][4w][64lane][32frag][8] f16
constexpr size_t OFF_B1    = OFF_WHH + (size_t)4 * 65536 * 2;       // [1024] f32 permuted bias
constexpr size_t OFF_B2    = OFF_B1 + 4096;                         // [1024] f32
constexpr size_t OFF_W1T   = OFF_B2 + 4096;                         // [512][512] f32 (transposed)
constexpr size_t OFF_W2T   = OFF_W1T + (size_t)512 * 512 * 4;
constexpr size_t OFF_POOL  = OFF_W2T + (size_t)512 * 512 * 4;       // [512][512] f32 (avg|max)
constexpr size_t OFF_H1    = OFF_POOL + (size_t)512 * 512 * 4;      // chunked region starts here (~10.7MB)
constexpr size_t H1_FULL   = (size_t)M_ * 256 * 2;                  // 67MB full
constexpr size_t XG_FULL   = (size_t)M_ * 1024 * 2;                 // 268MB full

DEVI void gload_lds16(const void* g, void* l) {
  __builtin_amdgcn_global_load_lds((const __attribute__((address_space(1))) void*)g,
                                   (__attribute__((address_space(3))) void*)l, 16, 0, 0);
}
DEVI float sigm(float x)  { return __builtin_amdgcn_rcpf(1.f + __expf(-x)); }
DEVI float tanh_(float x) { return 1.f - 2.f * __builtin_amdgcn_rcpf(1.f + __expf(2.f * x)); }

// Gate-row permutation: j' = wave*128 + gate*32 + k''  ->  orig = gate*128 + wave*32 + k''
DEVI int orig_row(int jp) {
  int wv = jp >> 7, rem = jp & 127;
  return (rem >> 5) * 128 + wv * 32 + (rem & 31);
}

// ---------------- prep: fp16 conversion, permutation, fragment pre-arrangement ----------------
__global__ void prep_kernel(
    const float* __restrict__ emb,
    const float* __restrict__ wih1f, const float* __restrict__ whh1f,
    const float* __restrict__ bih1f, const float* __restrict__ bhh1f,
    const float* __restrict__ wih1b, const float* __restrict__ whh1b,
    const float* __restrict__ bih1b, const float* __restrict__ bhh1b,
    const float* __restrict__ wih2f, const float* __restrict__ whh2f,
    const float* __restrict__ bih2f, const float* __restrict__ bhh2f,
    const float* __restrict__ wih2b, const float* __restrict__ whh2b,
    const float* __restrict__ bih2b, const float* __restrict__ bhh2b,
    const float* __restrict__ w1, const float* __restrict__ w2,
    char* __restrict__ ws)
{
  f16* emb16   = (f16*)(ws + OFF_EMB16);
  f16* wih1p   = (f16*)(ws + OFF_WIH1);
  f16* wih2p   = (f16*)(ws + OFF_WIH2);
  f16* whhp    = (f16*)(ws + OFF_WHH);
  float* b1p   = (float*)(ws + OFF_B1);
  float* b2p   = (float*)(ws + OFF_B2);
  float* w1t   = (float*)(ws + OFF_W1T);
  float* w2t   = (float*)(ws + OFF_W2T);
  const int64_t stride = (int64_t)gridDim.x * blockDim.x;
  const int64_t t0 = (int64_t)blockIdx.x * blockDim.x + threadIdx.x;

  for (int64_t i = t0; i < (int64_t)10000 * 320; i += stride) {
    int r = (int)(i / 320), c = (int)(i % 320);
    emb16[i] = (c < 300) ? (f16)emb[r * 300 + c] : (f16)0.f;
  }
  for (int64_t i = t0; i < 1024 * 320; i += stride) {
    int n = (int)(i / 320), k = (int)(i % 320);
    int d = n >> 9; int orig = orig_row(n & 511);
    const float* src = d ? wih1b : wih1f;
    wih1p[i] = (k < 300) ? (f16)src[orig * 300 + k] : (f16)0.f;
  }
  for (int64_t i = t0; i < 1024 * 256; i += stride) {
    int n = (int)(i / 256), k = (int)(i % 256);
    int d = n >> 9; int orig = orig_row(n & 511);
    const float* src = d ? wih2b : wih2f;
    wih2p[i] = (f16)src[orig * 256 + k];
  }
  // W_hh as per-lane MFMA B-fragments. idx = ((ld*4+w)*64+lane)*256 + f*8 + e
  for (int64_t i = t0; i < (int64_t)4 * 65536; i += stride) {
    int ld = (int)(i >> 16);              // layer*2 + dir
    int rem = (int)(i & 65535);
    int wl = rem >> 8; int w_ = wl >> 6, lane_ = wl & 63;
    int fe = rem & 255; int f_ = fe >> 3, e_ = fe & 7;
    int j_ = f_ >> 2, kk_ = f_ & 3;
    int nn = j_ * 16 + (lane_ & 15);
    int orig = (nn >> 5) * 128 + w_ * 32 + (nn & 31);
    int k = kk_ * 32 + (lane_ >> 4) * 8 + e_;
    const float* src = (ld == 0) ? whh1f : (ld == 1) ? whh1b : (ld == 2) ? whh2f : whh2b;
    whhp[i] = (f16)src[orig * 128 + k];
  }
  for (int64_t i = t0; i < 1024; i += stride) {
    int d = (int)(i >> 9); int orig = orig_row((int)(i & 511));
    b1p[i] = d ? (bih1b[orig] + bhh1b[orig]) : (bih1f[orig] + bhh1f[orig]);
    b2p[i] = d ? (bih2b[orig] + bhh2b[orig]) : (bih2f[orig] + bhh2f[orig]);
  }
  for (int64_t i = t0; i < 512 * 512; i += stride) {
    int k = (int)(i >> 9), j = (int)(i & 511);
    w1t[i] = w1[j * 512 + k];
    w2t[i] = w2[j * 512 + k];
  }
}

// ---------------- input-gate GEMM: xg_local[m][1024] = A[m][K] @ W^T + bias ----------------
// 128x128 tile, BK=64, 4 waves (2x2 of 64x64), global_load_lds w=16, XOR-swizzled LDS.
// mt0 = global M-tile base of this chunk; A rows and xg rows are chunk-local except the gather.
template<int KT, bool GATHER>
__global__ __launch_bounds__(256, 2) void gemm_xg(
    const f16* __restrict__ Asrc, const int* __restrict__ xtok,
    const f16* __restrict__ Bw, const float* __restrict__ bias,
    f16* __restrict__ xg, int mt0)
{
  __shared__ __align__(16) f16 lA[128 * 64];
  __shared__ __align__(16) f16 lB[128 * 64];
  const int tid = threadIdx.x;
  const int w = tid >> 6, lane = tid & 63;
  const int mt = blockIdx.x >> 3, nt = blockIdx.x & 7;   // mt = local tile
  const int wm = w & 1, wn = w >> 1;
  const int l3 = lane >> 3, l7 = lane & 7;
  const int c0 = lane & 15, kg = lane >> 4;
  const int swz = l7 ^ l3;

  const f16* asrc[4];
  const f16* bsrc[4];
#pragma unroll
  for (int c = 0; c < 4; ++c) {
    int r = c * 32 + w * 8 + l3;
    int arow;
    if constexpr (GATHER) arow = xtok[(mt0 + mt) * 128 + r];  // global token
    else                  arow = mt * 128 + r;                 // chunk-local h1 row
    asrc[c] = Asrc + (size_t)arow * (KT * 64) + swz * 8;
    bsrc[c] = Bw + (size_t)(nt * 128 + r) * (KT * 64) + swz * 8;
  }

  f32x4 acc[4][4] = {};
  for (int kk = 0; kk < KT; ++kk) {
#pragma unroll
    for (int c = 0; c < 4; ++c)
      gload_lds16(asrc[c] + kk * 64, &lA[(c * 256 + w * 64) * 8]);
#pragma unroll
    for (int c = 0; c < 4; ++c)
      gload_lds16(bsrc[c] + kk * 64, &lB[(c * 256 + w * 64) * 8]);
    asm volatile("s_waitcnt vmcnt(0)" ::: "memory");
    __builtin_amdgcn_s_barrier();

    f16x8 af[2][4], bf[2][4];
#pragma unroll
    for (int s = 0; s < 2; ++s)
#pragma unroll
      for (int i = 0; i < 4; ++i) {
        int ra = wm * 64 + i * 16 + c0;
        int rb = wn * 64 + i * 16 + c0;
        int u = (s * 4 + kg) ^ l7;
        af[s][i] = *(const f16x8*)&lA[ra * 64 + u * 8];
        bf[s][i] = *(const f16x8*)&lB[rb * 64 + u * 8];
      }
#pragma unroll
    for (int s = 0; s < 2; ++s)
#pragma unroll
      for (int i = 0; i < 4; ++i)
#pragma unroll
        for (int j = 0; j < 4; ++j)
          acc[i][j] = __builtin_amdgcn_mfma_f32_16x16x32_f16(af[s][i], bf[s][j], acc[i][j], 0, 0, 0);
    asm volatile("s_waitcnt lgkmcnt(0)" ::: "memory");
    __builtin_amdgcn_s_barrier();
  }

  float bj[4];
#pragma unroll
  for (int j = 0; j < 4; ++j) bj[j] = bias[nt * 128 + wn * 64 + j * 16 + c0];
#pragma unroll
  for (int i = 0; i < 4; ++i) {
    int mrow = mt * 128 + wm * 64 + i * 16 + kg * 4;     // chunk-local
#pragma unroll
    for (int j = 0; j < 4; ++j) {
      int col = nt * 128 + wn * 64 + j * 16 + c0;
#pragma unroll
      for (int r = 0; r < 4; ++r)
        xg[(size_t)(mrow + r) * 1024 + col] = (f16)(acc[i][j][r] + bj[j]);
    }
  }
}

// ---------------- LSTM recurrence: per block (dir, 16-batch group), W_hh in VGPRs ----------------
// xg is chunk-local [Bc*256][1024]; h1 chunk-local [Bc*256][256]; pool global (b0 offset).
template<int IS_L2>
__global__ __launch_bounds__(256, 1) void recur_kernel(
    const f16* __restrict__ xg, const f16* __restrict__ wf_base,
    f16* __restrict__ h1, float* __restrict__ pool, int b0, int nb16)
{
  const int tid = threadIdx.x;
  const int w = tid >> 6, lane = tid & 63;
  const int dir = blockIdx.x / nb16, ci = blockIdx.x % nb16;
  const int l7 = lane & 7, c0 = lane & 15, kg = lane >> 4;

  __shared__ __align__(16) f16 hbuf[16 * 128];         // [row 16][128] XOR-swizzled
  __shared__ __align__(16) f16 xbuf[2][4][2048];       // [dbuf][wave][16 rows][128] swizzled

  f16x8 Wf[32];                                        // whole W_hh N-slice, resident in VGPRs
  {
    const f16x8* wp = (const f16x8*)(wf_base + (size_t)((dir * 4 + w) * 64 + lane) * 256);
#pragma unroll
    for (int f = 0; f < 32; ++f) Wf[f] = wp[f];
  }
  { f16x8 z = {}; *(f16x8*)&hbuf[tid * 8] = z; }
  __syncthreads();

  const char* xgb = (const char*)xg;
  size_t sbase[4];
#pragma unroll
  for (int c = 0; c < 4; ++c) {
    int row = c * 4 + kg;                              // staged row (group-local batch)
    int logical = c0 ^ ((c & 1) * 4 + kg);             // pre-swizzled source unit (m173 pattern)
    sbase[c] = (size_t)(ci * 16 + row) * 524288 + (size_t)dir * 1024 + w * 256 + logical * 16;
  }
  auto stage = [&](int t, int buf) {
#pragma unroll
    for (int c = 0; c < 4; ++c)
      gload_lds16(xgb + sbase[c] + (size_t)t * 2048, &xbuf[buf][w][c * 512]);
  };

  float cst[8]  = {0, 0, 0, 0, 0, 0, 0, 0};
  float psum[8] = {0, 0, 0, 0, 0, 0, 0, 0};
  float pmax[8] = {-1e30f, -1e30f, -1e30f, -1e30f, -1e30f, -1e30f, -1e30f, -1e30f};

  stage(dir ? 255 : 0, 0);
  asm volatile("s_waitcnt vmcnt(0)" ::: "memory");     // one-time drain: buf0 resident

  for (int step = 0; step < 256; ++step) {
    const int t = dir ? (255 - step) : step;
    const int tn = dir ? (t ? t - 1 : 0) : (t < 255 ? t + 1 : 255);
    const int buf = step & 1;
    stage(tn, buf ^ 1);                                // prefetch, stays in flight (T4)

    f16x8 a[4];
#pragma unroll
    for (int q = 0; q < 4; ++q) {
      int u = (q * 4 + kg) ^ l7;                       // l7 == (row c0)&7
      a[q] = *(const f16x8*)&hbuf[c0 * 128 + u * 8];
    }
    f32x4 acc[8] = {};
#pragma unroll
    for (int j = 0; j < 8; ++j)
#pragma unroll
      for (int q = 0; q < 4; ++q)
        acc[j] = __builtin_amdgcn_mfma_f32_16x16x32_f16(a[q], Wf[j * 4 + q], acc[j], 0, 0, 0);

    asm volatile("s_waitcnt lgkmcnt(0)" ::: "memory"); // all hbuf reads done
    __builtin_amdgcn_s_barrier();                      // before overwriting hbuf
    asm volatile("s_waitcnt vmcnt(4)" ::: "memory");   // current xg tile landed; prefetch flying
    __builtin_amdgcn_sched_barrier(0);

    const f16* xb = &xbuf[buf][w][0];
#pragma unroll
    for (int r = 0; r < 4; ++r) {
      const int rbat = kg * 4 + r;
      const int rx = rbat & 7;
      const int cu = c0 >> 3, cl = c0 & 7;
#pragma unroll
      for (int p = 0; p < 2; ++p) {
        float xi  = (float)xb[rbat * 128 + (((0 + p * 2 + cu) ^ rx) * 8) + cl];
        float xf  = (float)xb[rbat * 128 + (((4 + p * 2 + cu) ^ rx) * 8) + cl];
        float xgg = (float)xb[rbat * 128 + (((8 + p * 2 + cu) ^ rx) * 8) + cl];
        float xo  = (float)xb[rbat * 128 + (((12 + p * 2 + cu) ^ rx) * 8) + cl];
        float gi = acc[0 + p][r] + xi;
        float gf = acc[2 + p][r] + xf;
        float gg = acc[4 + p][r] + xgg;
        float go = acc[6 + p][r] + xo;
        float si = sigm(gi), sf = sigm(gf), so = sigm(go);
        float cn = sf * cst[r * 2 + p] + si * tanh_(gg);
        cst[r * 2 + p] = cn;
        float hv = so * tanh_(cn);
        int k = w * 32 + p * 16 + c0;
        hbuf[rbat * 128 + (((k >> 3) ^ rx) * 8) + (k & 7)] = (f16)hv;
        if constexpr (IS_L2) {
          psum[r * 2 + p] += hv;
          pmax[r * 2 + p] = fmaxf(pmax[r * 2 + p], hv);
        }
      }
    }
    asm volatile("s_waitcnt lgkmcnt(0)" ::: "memory"); // hbuf writes visible
    __builtin_amdgcn_s_barrier();

    if constexpr (!IS_L2) {
      // coalesced h(t) writeback: one f16x8 store per thread from synced hbuf
      int rr = tid >> 4, uu = tid & 15;
      f16x8 hv8 = *(const f16x8*)&hbuf[rr * 128 + uu * 8];
      int col = (uu ^ (rr & 7)) * 8;                   // undo swizzle
      *(f16x8*)&h1[((size_t)(ci * 16 + rr) * 256 + t) * 256 + dir * 128 + col] = hv8;
    }
  }

  if constexpr (IS_L2) {
#pragma unroll
    for (int r = 0; r < 4; ++r)
#pragma unroll
      for (int p = 0; p < 2; ++p) {
        int k = w * 32 + p * 16 + c0;
        int b = b0 + ci * 16 + kg * 4 + r;
        pool[(size_t)b * 512 + dir * 128 + k] = psum[r * 2 + p] * (1.f / 256.f);
        pool[(size_t)b * 512 + 256 + dir * 128 + k] = pmax[r * 2 + p];
      }
  }
}

// ---------------- head: dense(512x512)x2 + residual + out/aux projections ----------------
__global__ __launch_bounds__(256) void head_kernel(
    const float* __restrict__ pool,
    const float* __restrict__ w1t, const float* __restrict__ w2t,
    const float* __restrict__ b1, const float* __restrict__ b2,
    const float* __restrict__ wout, const float* __restrict__ bout,
    const float* __restrict__ waux, const float* __restrict__ baux,
    float* __restrict__ out)
{
  __shared__ float hc[4][512];
  __shared__ float hid[4][512];
  const int tid = threadIdx.x;
  const int rb = blockIdx.x * 4;
  for (int i = tid; i < 2048; i += 256) hc[i >> 9][i & 511] = pool[(size_t)rb * 512 + i];
  __syncthreads();

  float acc1[2][4] = {}, acc2[2][4] = {};
  for (int k = 0; k < 512; ++k) {
    float w1a = w1t[k * 512 + tid], w1b = w1t[k * 512 + tid + 256];
    float w2a = w2t[k * 512 + tid], w2b = w2t[k * 512 + tid + 256];
#pragma unroll
    for (int r = 0; r < 4; ++r) {
      float h = hc[r][k];
      acc1[0][r] += w1a * h; acc1[1][r] += w1b * h;
      acc2[0][r] += w2a * h; acc2[1][r] += w2b * h;
    }
  }
#pragma unroll
  for (int r = 0; r < 4; ++r) {
    hid[r][tid] = fmaxf(acc1[0][r] + b1[tid], 0.f) + hc[r][tid] + fmaxf(acc2[0][r] + b2[tid], 0.f);
    hid[r][tid + 256] = fmaxf(acc1[1][r] + b1[tid + 256], 0.f) + hc[r][tid + 256]
                      + fmaxf(acc2[1][r] + b2[tid + 256], 0.f);
  }
  __syncthreads();

  const int wv = tid >> 6, lane = tid & 63;
  for (int o = 0; o < 7; ++o) {
    const float* wrow = (o == 0) ? wout : (waux + (size_t)(o - 1) * 512);
    float s = 0.f;
#pragma unroll
    for (int m = 0; m < 8; ++m) s += hid[wv][lane + 64 * m] * wrow[lane + 64 * m];
#pragma unroll
    for (int off = 32; off >= 1; off >>= 1) s += __shfl_xor(s, off, 64);
    if (lane == 0) out[(size_t)(rb + wv) * 7 + o] = s + ((o == 0) ? bout[0] : baux[o - 1]);
  }
}

// ---------------- launcher ----------------
extern "C" void kernel_launch(void* const* d_in, const int* in_sizes, int n_in,
                              void* d_out, int out_size, void* d_ws, size_t ws_size,
                              hipStream_t stream) {
  const int*   x     = (const int*)d_in[0];
  const float* emb   = (const float*)d_in[1];
  const float* wih1f = (const float*)d_in[2];
  const float* whh1f = (const float*)d_in[3];
  const float* bih1f = (const float*)d_in[4];
  const float* bhh1f = (const float*)d_in[5];
  const float* wih1b = (const float*)d_in[6];
  const float* whh1b = (const float*)d_in[7];
  const float* bih1b = (const float*)d_in[8];
  const float* bhh1b = (const float*)d_in[9];
  const float* wih2f = (const float*)d_in[10];
  const float* whh2f = (const float*)d_in[11];
  const float* bih2f = (const float*)d_in[12];
  const float* bhh2f = (const float*)d_in[13];
  const float* wih2b = (const float*)d_in[14];
  const float* whh2b = (const float*)d_in[15];
  const float* bih2b = (const float*)d_in[16];
  const float* bhh2b = (const float*)d_in[17];
  const float* w1    = (const float*)d_in[18];
  const float* b1    = (const float*)d_in[19];
  const float* w2    = (const float*)d_in[20];
  const float* b2    = (const float*)d_in[21];
  const float* wout  = (const float*)d_in[22];
  const float* bout  = (const float*)d_in[23];
  const float* waux  = (const float*)d_in[24];
  const float* baux  = (const float*)d_in[25];

  char* ws = (char*)d_ws;
  f16* emb16 = (f16*)(ws + OFF_EMB16);
  f16* wih1p = (f16*)(ws + OFF_WIH1);
  f16* wih2p = (f16*)(ws + OFF_WIH2);
  f16* whhp  = (f16*)(ws + OFF_WHH);
  float* b1p = (float*)(ws + OFF_B1);
  float* b2p = (float*)(ws + OFF_B2);
  float* w1t = (float*)(ws + OFF_W1T);
  float* w2t = (float*)(ws + OFF_W2T);
  float* pool = (float*)(ws + OFF_POOL);

  // choose chunk factor G (pure function of ws_size -> identical sequence every call)
  int G = 1;
  while (G < 32 && OFF_H1 + (H1_FULL + XG_FULL) / (size_t)G > ws_size) G <<= 1;
  const int Bc = BATCH / G;                 // batch per chunk
  f16* h1c = (f16*)(ws + OFF_H1);
  f16* xgc = (f16*)(ws + OFF_H1 + H1_FULL / (size_t)G);

  prep_kernel<<<4096, 256, 0, stream>>>(emb,
      wih1f, whh1f, bih1f, bhh1f, wih1b, whh1b, bih1b, bhh1b,
      wih2f, whh2f, bih2f, bhh2f, wih2b, whh2b, bih2b, bhh2b,
      w1, w2, ws);

  for (int g = 0; g < G; ++g) {
    const int b0 = g * Bc;
    const int mt0 = b0 * 2;                 // 256 rows per batch elem = 2 M-tiles
    const int mtiles = Bc * 2;
    const int nb16 = Bc / 16;
    gemm_xg<5, true><<<mtiles * 8, 256, 0, stream>>>(emb16, x, wih1p, b1p, xgc, mt0);
    recur_kernel<0><<<2 * nb16, 256, 0, stream>>>(xgc, whhp, h1c, nullptr, b0, nb16);
    gemm_xg<4, false><<<mtiles * 8, 256, 0, stream>>>(h1c, nullptr, wih2p, b2p, xgc, mt0);
    recur_kernel<1><<<2 * nb16, 256, 0, stream>>>(xgc, whhp + 2 * 65536, nullptr, pool, b0, nb16);
  }

  head_kernel<<<128, 256, 0, stream>>>(pool, w1t, w2t, b1, b2, wout, bout, waux, baux,
                                       (float*)d_out);
}

// Round 3
// 1467.307 us; speedup vs baseline: 1.4721x; 1.4721x over previous
//
#include <hip/hip_runtime.h>
#include <cstdint>
#include <cstddef>

typedef _Float16 f16;
typedef _Float16 f16x8 __attribute__((ext_vector_type(8)));
typedef _Float16 f16x4 __attribute__((ext_vector_type(4)));
typedef float f32x4 __attribute__((ext_vector_type(4)));

#define DEVI __device__ __forceinline__

// ---------------- problem sizes ----------------
constexpr int T_ = 256;
constexpr int BATCH = 512;
constexpr int M_ = BATCH * T_;   // 131072 tokens
constexpr int KE_ = 320;         // layer-1 K (300 padded to 320)
constexpr int K2_ = 256;         // layer-2 K

// ---------------- fixed ws region (bytes, all 16B aligned) ----------------
constexpr size_t OFF_EMB16 = 0;                                     // [10000][320] f16
constexpr size_t OFF_WIH1  = OFF_EMB16 + (size_t)10000 * KE_ * 2;   // [1024][320] f16 (tile-permuted)
constexpr size_t OFF_WIH2  = OFF_WIH1 + (size_t)1024 * KE_ * 2;     // [1024][256] f16
constexpr size_t OFF_WHH   = OFF_WIH2 + (size_t)1024 * K2_ * 2;     // [4 ld][8w][64lane][16frag][8] f16
constexpr size_t OFF_B1    = OFF_WHH + (size_t)4 * 65536 * 2;       // [1024] f32 permuted bias
constexpr size_t OFF_B2    = OFF_B1 + 4096;                         // [1024] f32
constexpr size_t OFF_W1T   = OFF_B2 + 4096;                         // [512][512] f32 (transposed)
constexpr size_t OFF_W2T   = OFF_W1T + (size_t)512 * 512 * 4;
constexpr size_t OFF_POOL  = OFF_W2T + (size_t)512 * 512 * 4;       // [512][512] f32 (avg|max)
constexpr size_t OFF_H1    = OFF_POOL + (size_t)512 * 512 * 4;      // chunked region (~10.7MB fixed above)
constexpr size_t H1_FULL   = (size_t)M_ * 256 * 2;                  // 67MB full
constexpr size_t XG_FULL   = (size_t)M_ * 1024 * 2;                 // 268MB full

DEVI void gload_lds16(const void* g, void* l) {
  __builtin_amdgcn_global_load_lds((const __attribute__((address_space(1))) void*)g,
                                   (__attribute__((address_space(3))) void*)l, 16, 0, 0);
}
DEVI float sigm(float x)  { return __builtin_amdgcn_rcpf(1.f + __expf(-x)); }
DEVI float tanh_(float x) { return 1.f - 2.f * __builtin_amdgcn_rcpf(1.f + __expf(2.f * x)); }

// xg col layout: col = dir*512 + unit*4 + gate   (gate contiguous, unit next)
// GEMM N-tile nt = dir*4 + ug  covers units [ug*32, ug*32+32) x 4 gates.
// within tile: r = wn*64 + j*16 + c0  ->  gate=j, unit=ug*32+wn*16+c0
// B-perm row p = nt*128 + r  ->  orig W row = gate*128 + unit  (per dir)
DEVI int borow(int p) {
  int r = p & 127;
  int ug = (p >> 7) & 3;
  int wn = r >> 6, j = (r >> 4) & 3, c0 = r & 15;
  return j * 128 + ug * 32 + wn * 16 + c0;
}

// ---------------- prep: fp16 conversion, permutation, fragment pre-arrangement ----------------
__global__ void prep_kernel(
    const float* __restrict__ emb,
    const float* __restrict__ wih1f, const float* __restrict__ whh1f,
    const float* __restrict__ bih1f, const float* __restrict__ bhh1f,
    const float* __restrict__ wih1b, const float* __restrict__ whh1b,
    const float* __restrict__ bih1b, const float* __restrict__ bhh1b,
    const float* __restrict__ wih2f, const float* __restrict__ whh2f,
    const float* __restrict__ bih2f, const float* __restrict__ bhh2f,
    const float* __restrict__ wih2b, const float* __restrict__ whh2b,
    const float* __restrict__ bih2b, const float* __restrict__ bhh2b,
    const float* __restrict__ w1, const float* __restrict__ w2,
    char* __restrict__ ws)
{
  f16* emb16   = (f16*)(ws + OFF_EMB16);
  f16* wih1p   = (f16*)(ws + OFF_WIH1);
  f16* wih2p   = (f16*)(ws + OFF_WIH2);
  f16* whhp    = (f16*)(ws + OFF_WHH);
  float* b1p   = (float*)(ws + OFF_B1);
  float* b2p   = (float*)(ws + OFF_B2);
  float* w1t   = (float*)(ws + OFF_W1T);
  float* w2t   = (float*)(ws + OFF_W2T);
  const int64_t stride = (int64_t)gridDim.x * blockDim.x;
  const int64_t t0 = (int64_t)blockIdx.x * blockDim.x + threadIdx.x;

  for (int64_t i = t0; i < (int64_t)10000 * 320; i += stride) {
    int r = (int)(i / 320), c = (int)(i % 320);
    emb16[i] = (c < 300) ? (f16)emb[r * 300 + c] : (f16)0.f;
  }
  for (int64_t i = t0; i < 1024 * 320; i += stride) {
    int p = (int)(i / 320), k = (int)(i % 320);
    int dir = p >> 9; int orig = borow(p & 511);
    const float* src = dir ? wih1b : wih1f;
    wih1p[i] = (k < 300) ? (f16)src[orig * 300 + k] : (f16)0.f;
  }
  for (int64_t i = t0; i < 1024 * 256; i += stride) {
    int p = (int)(i / 256), k = (int)(i % 256);
    int dir = p >> 9; int orig = borow(p & 511);
    const float* src = dir ? wih2b : wih2f;
    wih2p[i] = (f16)src[orig * 256 + k];
  }
  // W_hh recur B-frags: [(ld*8 + w)*64 + lane][frag f=g*4+kk][e]
  //   N-row = g*128 + w*16 + (lane&15);  k = kk*32 + (lane>>4)*8 + e
  for (int64_t i = t0; i < (int64_t)4 * 65536; i += stride) {
    int ld = (int)(i >> 16);              // layer*2 + dir
    int rem = (int)(i & 65535);
    int rec = rem >> 7;                    // w*64 + lane
    int w_ = rec >> 6, lane_ = rec & 63;
    int fe = rem & 127; int f_ = fe >> 3, e_ = fe & 7;
    int g_ = f_ >> 2, kk_ = f_ & 3;
    int n = g_ * 128 + w_ * 16 + (lane_ & 15);
    int k = kk_ * 32 + (lane_ >> 4) * 8 + e_;
    const float* src = (ld == 0) ? whh1f : (ld == 1) ? whh1b : (ld == 2) ? whh2f : whh2b;
    whhp[i] = (f16)src[n * 128 + k];
  }
  for (int64_t i = t0; i < 1024; i += stride) {
    int dir = (int)(i >> 9); int orig = borow((int)(i & 511));
    b1p[i] = dir ? (bih1b[orig] + bhh1b[orig]) : (bih1f[orig] + bhh1f[orig]);
    b2p[i] = dir ? (bih2b[orig] + bhh2b[orig]) : (bih2f[orig] + bhh2f[orig]);
  }
  for (int64_t i = t0; i < 512 * 512; i += stride) {
    int k = (int)(i >> 9), j = (int)(i & 511);
    w1t[i] = w1[j * 512 + k];
    w2t[i] = w2[j * 512 + k];
  }
}

// ---------------- input-gate GEMM: packed-layout xg, double-buffered LDS ----------------
template<int KT, bool GATHER>
__global__ __launch_bounds__(256, 2) void gemm_xg(
    const f16* __restrict__ Asrc, const int* __restrict__ xtok,
    const f16* __restrict__ Bw, const float* __restrict__ bias,
    f16* __restrict__ xg, int mt0)
{
  __shared__ __align__(16) f16 lA[2][8192];
  __shared__ __align__(16) f16 lB[2][8192];
  const int tid = threadIdx.x;
  const int w = tid >> 6, lane = tid & 63;
  const int mt = blockIdx.x >> 3, nt = blockIdx.x & 7;   // mt = chunk-local tile
  const int wm = w & 1, wn = w >> 1;
  const int l3 = lane >> 3, l7 = lane & 7;
  const int c0 = lane & 15, kg = lane >> 4;
  const int swz = l7 ^ l3;

  const f16* asrc[4];
  const f16* bsrc[4];
#pragma unroll
  for (int c = 0; c < 4; ++c) {
    int r = c * 32 + w * 8 + l3;
    int arow;
    if constexpr (GATHER) arow = xtok[(mt0 + mt) * 128 + r];  // global token id
    else                  arow = mt * 128 + r;                 // chunk-local h1 row
    asrc[c] = Asrc + (size_t)arow * (KT * 64) + swz * 8;
    bsrc[c] = Bw + (size_t)(nt * 128 + r) * (KT * 64) + swz * 8;
  }
  auto stage = [&](int kk, int d) {
#pragma unroll
    for (int c = 0; c < 4; ++c)
      gload_lds16(asrc[c] + kk * 64, &lA[d][(c * 256 + w * 64) * 8]);
#pragma unroll
    for (int c = 0; c < 4; ++c)
      gload_lds16(bsrc[c] + kk * 64, &lB[d][(c * 256 + w * 64) * 8]);
  };

  f32x4 acc[4][4] = {};
  stage(0, 0);
  for (int kk = 0; kk < KT; ++kk) {
    const int d = kk & 1;
    if (kk + 1 < KT) {
      stage(kk + 1, d ^ 1);
      asm volatile("s_waitcnt vmcnt(8)" ::: "memory");   // current tile landed, next in flight
    } else {
      asm volatile("s_waitcnt vmcnt(0)" ::: "memory");
    }
    __builtin_amdgcn_s_barrier();

    f16x8 af[2][4], bf[2][4];
#pragma unroll
    for (int s = 0; s < 2; ++s)
#pragma unroll
      for (int i = 0; i < 4; ++i) {
        int ra = wm * 64 + i * 16 + c0;
        int rb = wn * 64 + i * 16 + c0;
        int u = (s * 4 + kg) ^ l7;
        af[s][i] = *(const f16x8*)&lA[d][ra * 64 + u * 8];
        bf[s][i] = *(const f16x8*)&lB[d][rb * 64 + u * 8];
      }
#pragma unroll
    for (int s = 0; s < 2; ++s)
#pragma unroll
      for (int i = 0; i < 4; ++i)
#pragma unroll
        for (int j = 0; j < 4; ++j)
          acc[i][j] = __builtin_amdgcn_mfma_f32_16x16x32_f16(af[s][i], bf[s][j], acc[i][j], 0, 0, 0);
    asm volatile("s_waitcnt lgkmcnt(0)" ::: "memory");
    __builtin_amdgcn_s_barrier();
  }

  // epilogue: lane acc[i][j][r] = (m = mt*128+wm*64+i*16+kg*4+r, gate=j, unit=ug*32+wn*16+c0)
  const int dir = nt >> 2, ug = nt & 3;
  const int unit = ug * 32 + wn * 16 + c0;
  float bj[4];
#pragma unroll
  for (int j = 0; j < 4; ++j) bj[j] = bias[nt * 128 + wn * 64 + j * 16 + c0];
#pragma unroll
  for (int i = 0; i < 4; ++i)
#pragma unroll
    for (int r = 0; r < 4; ++r) {
      int m = mt * 128 + wm * 64 + i * 16 + kg * 4 + r;
      f16x4 v = { (f16)(acc[i][0][r] + bj[0]), (f16)(acc[i][1][r] + bj[1]),
                  (f16)(acc[i][2][r] + bj[2]), (f16)(acc[i][3][r] + bj[3]) };
      *(f16x4*)&xg[(size_t)m * 1024 + dir * 512 + unit * 4] = v;
    }
}

// ---------------- LSTM recurrence v2: 8 waves, xg via registers, W_hh resident ----------------
// block = (dir, 16-batch group); wave w owns units [w*16, w*16+16) x 4 gates.
template<int IS_L2>
__global__ __launch_bounds__(512, 2) void recur_kernel(
    const f16* __restrict__ xg, const f16* __restrict__ wf_base,
    f16* __restrict__ h1, float* __restrict__ pool, int b0, int nb16)
{
  const int tid = threadIdx.x;
  const int w = tid >> 6, lane = tid & 63;
  const int dir = blockIdx.x / nb16, ci = blockIdx.x % nb16;
  const int l7 = lane & 7, c0 = lane & 15, kg = lane >> 4;

  __shared__ __align__(16) f16 hbuf[16 * 128];          // [row16][128 units] XOR-swizzled (8-f16 units)

  f16x8 Wf[16];                                         // this wave's W_hh B-frags (64 VGPR)
  {
    const f16x8* wp = (const f16x8*)(wf_base + (size_t)((dir * 8 + w) * 64 + lane) * 128);
#pragma unroll
    for (int f = 0; f < 16; ++f) Wf[f] = wp[f];
  }
  if (tid < 256) { f16x8 z = {}; *(f16x8*)&hbuf[tid * 8] = z; }
  __syncthreads();

  const int unit = w * 16 + c0;
  const int u8 = unit >> 3, uoff = unit & 7;
  const f16* xga = xg + (size_t)dir * 512 + (size_t)unit * 4;

  auto ldx = [&](int t, f16x4* dst) {
#pragma unroll
    for (int r = 0; r < 4; ++r)
      dst[r] = *(const f16x4*)(xga + ((size_t)(ci * 16 + kg * 4 + r) * 256 + t) * 1024);
  };

  float cst[4]  = {0, 0, 0, 0};
  float psum[4] = {0, 0, 0, 0};
  float pmax[4] = {-1e30f, -1e30f, -1e30f, -1e30f};

  f16x4 xa[4], xb[4];
  ldx(dir ? 255 : 0, xa);

  auto body = [&](int step, f16x4* cur, f16x4* nxt) {
    const int t = dir ? (255 - step) : step;
    const int sn = (step + 1 < 256) ? step + 1 : 255;
    ldx(dir ? (255 - sn) : sn, nxt);                    // prefetch next step (reg dbuf)

    f16x8 a[4];
#pragma unroll
    for (int q = 0; q < 4; ++q) {
      int u = (q * 4 + kg) ^ l7;                        // l7 == (A-row c0)&7
      a[q] = *(const f16x8*)&hbuf[c0 * 128 + u * 8];
    }
    f32x4 acc[4] = {};
#pragma unroll
    for (int g = 0; g < 4; ++g)
#pragma unroll
      for (int q = 0; q < 4; ++q)
        acc[g] = __builtin_amdgcn_mfma_f32_16x16x32_f16(a[q], Wf[g * 4 + q], acc[g], 0, 0, 0);

    asm volatile("s_waitcnt lgkmcnt(0)" ::: "memory");  // hbuf reads done
    __builtin_amdgcn_s_barrier();                       // now safe to overwrite hbuf

#pragma unroll
    for (int r = 0; r < 4; ++r) {
      float gi = acc[0][r] + (float)cur[r][0];
      float gf = acc[1][r] + (float)cur[r][1];
      float gG = acc[2][r] + (float)cur[r][2];
      float go = acc[3][r] + (float)cur[r][3];
      float si = sigm(gi), sf = sigm(gf), so = sigm(go);
      float cn = sf * cst[r] + si * tanh_(gG);
      cst[r] = cn;
      float hv = so * tanh_(cn);
      int row = kg * 4 + r;
      hbuf[row * 128 + ((u8 ^ (row & 7)) * 8) + uoff] = (f16)hv;
      if constexpr (IS_L2) {
        psum[r] += hv;
        pmax[r] = fmaxf(pmax[r], hv);
      }
    }
    asm volatile("s_waitcnt lgkmcnt(0)" ::: "memory");  // hbuf writes visible
    __builtin_amdgcn_s_barrier();

    if constexpr (!IS_L2) {
      // coalesced h(t) writeback: 512 threads x f16x4 from synced hbuf
      int row = tid >> 5, qd = tid & 31;
      int ub = qd >> 1, off4 = (qd & 1) * 4;
      f16x4 hv4 = *(const f16x4*)&hbuf[row * 128 + ((ub ^ (row & 7)) * 8) + off4];
      *(f16x4*)&h1[((size_t)(ci * 16 + row) * 256 + t) * 256 + dir * 128 + qd * 4] = hv4;
    }
  };

  for (int s2 = 0; s2 < 128; ++s2) {                    // manual 2x unroll: static reg dbuf
    body(2 * s2, xa, xb);
    body(2 * s2 + 1, xb, xa);
  }

  if constexpr (IS_L2) {
#pragma unroll
    for (int r = 0; r < 4; ++r) {
      int b = b0 + ci * 16 + kg * 4 + r;
      pool[(size_t)b * 512 + dir * 128 + unit] = psum[r] * (1.f / 256.f);
      pool[(size_t)b * 512 + 256 + dir * 128 + unit] = pmax[r];
    }
  }
}

// ---------------- head: dense(512x512)x2 + residual + out/aux projections ----------------
__global__ __launch_bounds__(256) void head_kernel(
    const float* __restrict__ pool,
    const float* __restrict__ w1t, const float* __restrict__ w2t,
    const float* __restrict__ b1, const float* __restrict__ b2,
    const float* __restrict__ wout, const float* __restrict__ bout,
    const float* __restrict__ waux, const float* __restrict__ baux,
    float* __restrict__ out)
{
  __shared__ float hc[4][512];
  __shared__ float hid[4][512];
  const int tid = threadIdx.x;
  const int rb = blockIdx.x * 4;
  for (int i = tid; i < 2048; i += 256) hc[i >> 9][i & 511] = pool[(size_t)rb * 512 + i];
  __syncthreads();

  float acc1[2][4] = {}, acc2[2][4] = {};
  for (int k = 0; k < 512; ++k) {
    float w1a = w1t[k * 512 + tid], w1b = w1t[k * 512 + tid + 256];
    float w2a = w2t[k * 512 + tid], w2b = w2t[k * 512 + tid + 256];
#pragma unroll
    for (int r = 0; r < 4; ++r) {
      float h = hc[r][k];
      acc1[0][r] += w1a * h; acc1[1][r] += w1b * h;
      acc2[0][r] += w2a * h; acc2[1][r] += w2b * h;
    }
  }
#pragma unroll
  for (int r = 0; r < 4; ++r) {
    hid[r][tid] = fmaxf(acc1[0][r] + b1[tid], 0.f) + hc[r][tid] + fmaxf(acc2[0][r] + b2[tid], 0.f);
    hid[r][tid + 256] = fmaxf(acc1[1][r] + b1[tid + 256], 0.f) + hc[r][tid + 256]
                      + fmaxf(acc2[1][r] + b2[tid + 256], 0.f);
  }
  __syncthreads();

  const int wv = tid >> 6, lane = tid & 63;
  for (int o = 0; o < 7; ++o) {
    const float* wrow = (o == 0) ? wout : (waux + (size_t)(o - 1) * 512);
    float s = 0.f;
#pragma unroll
    for (int m = 0; m < 8; ++m) s += hid[wv][lane + 64 * m] * wrow[lane + 64 * m];
#pragma unroll
    for (int off = 32; off >= 1; off >>= 1) s += __shfl_xor(s, off, 64);
    if (lane == 0) out[(size_t)(rb + wv) * 7 + o] = s + ((o == 0) ? bout[0] : baux[o - 1]);
  }
}

// ---------------- launcher ----------------
extern "C" void kernel_launch(void* const* d_in, const int* in_sizes, int n_in,
                              void* d_out, int out_size, void* d_ws, size_t ws_size,
                              hipStream_t stream) {
  const int*   x     = (const int*)d_in[0];
  const float* emb   = (const float*)d_in[1];
  const float* wih1f = (const float*)d_in[2];
  const float* whh1f = (const float*)d_in[3];
  const float* bih1f = (const float*)d_in[4];
  const float* bhh1f = (const float*)d_in[5];
  const float* wih1b = (const float*)d_in[6];
  const float* whh1b = (const float*)d_in[7];
  const float* bih1b = (const float*)d_in[8];
  const float* bhh1b = (const float*)d_in[9];
  const float* wih2f = (const float*)d_in[10];
  const float* whh2f = (const float*)d_in[11];
  const float* bih2f = (const float*)d_in[12];
  const float* bhh2f = (const float*)d_in[13];
  const float* wih2b = (const float*)d_in[14];
  const float* whh2b = (const float*)d_in[15];
  const float* bih2b = (const float*)d_in[16];
  const float* bhh2b = (const float*)d_in[17];
  const float* w1    = (const float*)d_in[18];
  const float* b1    = (const float*)d_in[19];
  const float* w2    = (const float*)d_in[20];
  const float* b2    = (const float*)d_in[21];
  const float* wout  = (const float*)d_in[22];
  const float* bout  = (const float*)d_in[23];
  const float* waux  = (const float*)d_in[24];
  const float* baux  = (const float*)d_in[25];

  char* ws = (char*)d_ws;
  f16* emb16 = (f16*)(ws + OFF_EMB16);
  f16* wih1p = (f16*)(ws + OFF_WIH1);
  f16* wih2p = (f16*)(ws + OFF_WIH2);
  f16* whhp  = (f16*)(ws + OFF_WHH);
  float* b1p = (float*)(ws + OFF_B1);
  float* b2p = (float*)(ws + OFF_B2);
  float* w1t = (float*)(ws + OFF_W1T);
  float* w2t = (float*)(ws + OFF_W2T);
  float* pool = (float*)(ws + OFF_POOL);

  // chunk factor G (pure function of ws_size -> identical sequence every call)
  int G = 1;
  while (G < 32 && OFF_H1 + (H1_FULL + XG_FULL) / (size_t)G > ws_size) G <<= 1;
  const int Bc = BATCH / G;                 // batch per chunk
  f16* h1c = (f16*)(ws + OFF_H1);
  f16* xgc = (f16*)(ws + OFF_H1 + H1_FULL / (size_t)G);

  prep_kernel<<<4096, 256, 0, stream>>>(emb,
      wih1f, whh1f, bih1f, bhh1f, wih1b, whh1b, bih1b, bhh1b,
      wih2f, whh2f, bih2f, bhh2f, wih2b, whh2b, bih2b, bhh2b,
      w1, w2, ws);

  for (int g = 0; g < G; ++g) {
    const int b0 = g * Bc;
    const int mt0 = b0 * 2;                 // 256 rows per batch elem = 2 M-tiles
    const int mtiles = Bc * 2;
    const int nb16 = Bc / 16;
    gemm_xg<5, true><<<mtiles * 8, 256, 0, stream>>>(emb16, x, wih1p, b1p, xgc, mt0);
    recur_kernel<0><<<2 * nb16, 512, 0, stream>>>(xgc, whhp, h1c, nullptr, b0, nb16);
    gemm_xg<4, false><<<mtiles * 8, 256, 0, stream>>>(h1c, nullptr, wih2p, b2p, xgc, mt0);
    recur_kernel<1><<<2 * nb16, 512, 0, stream>>>(xgc, whhp + 2 * 65536, nullptr, pool, b0, nb16);
  }

  head_kernel<<<128, 256, 0, stream>>>(pool, w1t, w2t, b1, b2, wout, bout, waux, baux,
                                       (float*)d_out);
}

// Round 4
// 1259.123 us; speedup vs baseline: 1.7155x; 1.1653x over previous
//
#include <hip/hip_runtime.h>
#include <cstdint>
#include <cstddef>

typedef _Float16 f16;
typedef _Float16 f16x8 __attribute__((ext_vector_type(8)));
typedef _Float16 f16x4 __attribute__((ext_vector_type(4)));
typedef float f32x4 __attribute__((ext_vector_type(4)));

#define DEVI __device__ __forceinline__

// ---------------- problem sizes ----------------
constexpr int T_ = 256;
constexpr int BATCH = 512;
constexpr int M_ = BATCH * T_;   // 131072 tokens
constexpr int KE_ = 320;         // layer-1 K (300 padded to 320)
constexpr int K2_ = 256;         // layer-2 K

// ---------------- fixed ws region (bytes, all 16B aligned) ----------------
constexpr size_t OFF_EMB16 = 0;                                     // [10000][320] f16
constexpr size_t OFF_WIH1  = OFF_EMB16 + (size_t)10000 * KE_ * 2;   // [1024][320] f16 (tile-permuted)
constexpr size_t OFF_WIH2  = OFF_WIH1 + (size_t)1024 * KE_ * 2;     // [1024][256] f16
constexpr size_t OFF_WHH   = OFF_WIH2 + (size_t)1024 * K2_ * 2;     // [4 ld][8w][64lane][16frag][8] f16
constexpr size_t OFF_B1    = OFF_WHH + (size_t)4 * 65536 * 2;       // [1024] f32 permuted bias
constexpr size_t OFF_B2    = OFF_B1 + 4096;                         // [1024] f32
constexpr size_t OFF_W1T   = OFF_B2 + 4096;                         // [512][512] f32 (transposed)
constexpr size_t OFF_W2T   = OFF_W1T + (size_t)512 * 512 * 4;
constexpr size_t OFF_POOL  = OFF_W2T + (size_t)512 * 512 * 4;       // [512][512] f32 (avg|max)
constexpr size_t OFF_H1    = OFF_POOL + (size_t)512 * 512 * 4;      // chunked region (~10.7MB fixed above)
constexpr size_t H1_FULL   = (size_t)M_ * 256 * 2;                  // 67MB full
constexpr size_t XG_FULL   = (size_t)M_ * 1024 * 2;                 // 268MB full

DEVI void gload_lds16(const void* g, void* l) {
  __builtin_amdgcn_global_load_lds((const __attribute__((address_space(1))) void*)g,
                                   (__attribute__((address_space(3))) void*)l, 16, 0, 0);
}
DEVI float sigm(float x)  { return __builtin_amdgcn_rcpf(1.f + __expf(-x)); }
DEVI float tanh_(float x) { return 1.f - 2.f * __builtin_amdgcn_rcpf(1.f + __expf(2.f * x)); }

// xg col layout: col = dir*512 + unit*4 + gate   (gate contiguous, unit next)
// GEMM N-tile nt = dir*4 + ug  covers units [ug*32, ug*32+32) x 4 gates.
// within tile: r = wn*64 + j*16 + c0  ->  gate=j, unit=ug*32+wn*16+c0
// B-perm row p = nt*128 + r  ->  orig W row = gate*128 + unit  (per dir)
DEVI int borow(int p) {
  int r = p & 127;
  int ug = (p >> 7) & 3;
  int wn = r >> 6, j = (r >> 4) & 3, c0 = r & 15;
  return j * 128 + ug * 32 + wn * 16 + c0;
}

// ---------------- prep: fp16 conversion, permutation, fragment pre-arrangement ----------------
__global__ void prep_kernel(
    const float* __restrict__ emb,
    const float* __restrict__ wih1f, const float* __restrict__ whh1f,
    const float* __restrict__ bih1f, const float* __restrict__ bhh1f,
    const float* __restrict__ wih1b, const float* __restrict__ whh1b,
    const float* __restrict__ bih1b, const float* __restrict__ bhh1b,
    const float* __restrict__ wih2f, const float* __restrict__ whh2f,
    const float* __restrict__ bih2f, const float* __restrict__ bhh2f,
    const float* __restrict__ wih2b, const float* __restrict__ whh2b,
    const float* __restrict__ bih2b, const float* __restrict__ bhh2b,
    const float* __restrict__ w1, const float* __restrict__ w2,
    char* __restrict__ ws)
{
  f16* emb16   = (f16*)(ws + OFF_EMB16);
  f16* wih1p   = (f16*)(ws + OFF_WIH1);
  f16* wih2p   = (f16*)(ws + OFF_WIH2);
  f16* whhp    = (f16*)(ws + OFF_WHH);
  float* b1p   = (float*)(ws + OFF_B1);
  float* b2p   = (float*)(ws + OFF_B2);
  float* w1t   = (float*)(ws + OFF_W1T);
  float* w2t   = (float*)(ws + OFF_W2T);
  const int64_t stride = (int64_t)gridDim.x * blockDim.x;
  const int64_t t0 = (int64_t)blockIdx.x * blockDim.x + threadIdx.x;

  for (int64_t i = t0; i < (int64_t)10000 * 320; i += stride) {
    int r = (int)(i / 320), c = (int)(i % 320);
    emb16[i] = (c < 300) ? (f16)emb[r * 300 + c] : (f16)0.f;
  }
  for (int64_t i = t0; i < 1024 * 320; i += stride) {
    int p = (int)(i / 320), k = (int)(i % 320);
    int dir = p >> 9; int orig = borow(p & 511);
    const float* src = dir ? wih1b : wih1f;
    wih1p[i] = (k < 300) ? (f16)src[orig * 300 + k] : (f16)0.f;
  }
  for (int64_t i = t0; i < 1024 * 256; i += stride) {
    int p = (int)(i / 256), k = (int)(i % 256);
    int dir = p >> 9; int orig = borow(p & 511);
    const float* src = dir ? wih2b : wih2f;
    wih2p[i] = (f16)src[orig * 256 + k];
  }
  // W_hh recur B-frags: [(ld*8 + w)*64 + lane][frag f=g*4+kk][e]
  //   N-row = g*128 + w*16 + (lane&15);  k = kk*32 + (lane>>4)*8 + e
  for (int64_t i = t0; i < (int64_t)4 * 65536; i += stride) {
    int ld = (int)(i >> 16);              // layer*2 + dir
    int rem = (int)(i & 65535);
    int rec = rem >> 7;                    // w*64 + lane
    int w_ = rec >> 6, lane_ = rec & 63;
    int fe = rem & 127; int f_ = fe >> 3, e_ = fe & 7;
    int g_ = f_ >> 2, kk_ = f_ & 3;
    int n = g_ * 128 + w_ * 16 + (lane_ & 15);
    int k = kk_ * 32 + (lane_ >> 4) * 8 + e_;
    const float* src = (ld == 0) ? whh1f : (ld == 1) ? whh1b : (ld == 2) ? whh2f : whh2b;
    whhp[i] = (f16)src[n * 128 + k];
  }
  for (int64_t i = t0; i < 1024; i += stride) {
    int dir = (int)(i >> 9); int orig = borow((int)(i & 511));
    b1p[i] = dir ? (bih1b[orig] + bhh1b[orig]) : (bih1f[orig] + bhh1f[orig]);
    b2p[i] = dir ? (bih2b[orig] + bhh2b[orig]) : (bih2f[orig] + bhh2f[orig]);
  }
  for (int64_t i = t0; i < 512 * 512; i += stride) {
    int k = (int)(i >> 9), j = (int)(i & 511);
    w1t[i] = w1[j * 512 + k];
    w2t[i] = w2[j * 512 + k];
  }
}

// ---------------- input-gate GEMM: packed-layout xg, double-buffered LDS ----------------
template<int KT, bool GATHER>
__global__ __launch_bounds__(256, 2) void gemm_xg(
    const f16* __restrict__ Asrc, const int* __restrict__ xtok,
    const f16* __restrict__ Bw, const float* __restrict__ bias,
    f16* __restrict__ xg, int mt0)
{
  __shared__ __align__(16) f16 lA[2][8192];
  __shared__ __align__(16) f16 lB[2][8192];
  const int tid = threadIdx.x;
  const int w = tid >> 6, lane = tid & 63;
  const int mt = blockIdx.x >> 3, nt = blockIdx.x & 7;   // mt = chunk-local tile
  const int wm = w & 1, wn = w >> 1;
  const int l3 = lane >> 3, l7 = lane & 7;
  const int c0 = lane & 15, kg = lane >> 4;
  const int swz = l7 ^ l3;

  const f16* asrc[4];
  const f16* bsrc[4];
#pragma unroll
  for (int c = 0; c < 4; ++c) {
    int r = c * 32 + w * 8 + l3;
    int arow;
    if constexpr (GATHER) arow = xtok[(mt0 + mt) * 128 + r];  // global token id
    else                  arow = mt * 128 + r;                 // chunk-local h1 row
    asrc[c] = Asrc + (size_t)arow * (KT * 64) + swz * 8;
    bsrc[c] = Bw + (size_t)(nt * 128 + r) * (KT * 64) + swz * 8;
  }
  auto stage = [&](int kk, int d) {
#pragma unroll
    for (int c = 0; c < 4; ++c)
      gload_lds16(asrc[c] + kk * 64, &lA[d][(c * 256 + w * 64) * 8]);
#pragma unroll
    for (int c = 0; c < 4; ++c)
      gload_lds16(bsrc[c] + kk * 64, &lB[d][(c * 256 + w * 64) * 8]);
  };

  f32x4 acc[4][4] = {};
  stage(0, 0);
  for (int kk = 0; kk < KT; ++kk) {
    const int d = kk & 1;
    if (kk + 1 < KT) {
      stage(kk + 1, d ^ 1);
      asm volatile("s_waitcnt vmcnt(8)" ::: "memory");   // current tile landed, next in flight
    } else {
      asm volatile("s_waitcnt vmcnt(0)" ::: "memory");
    }
    __builtin_amdgcn_s_barrier();

    f16x8 af[2][4], bf[2][4];
#pragma unroll
    for (int s = 0; s < 2; ++s)
#pragma unroll
      for (int i = 0; i < 4; ++i) {
        int ra = wm * 64 + i * 16 + c0;
        int rb = wn * 64 + i * 16 + c0;
        int u = (s * 4 + kg) ^ l7;
        af[s][i] = *(const f16x8*)&lA[d][ra * 64 + u * 8];
        bf[s][i] = *(const f16x8*)&lB[d][rb * 64 + u * 8];
      }
#pragma unroll
    for (int s = 0; s < 2; ++s)
#pragma unroll
      for (int i = 0; i < 4; ++i)
#pragma unroll
        for (int j = 0; j < 4; ++j)
          acc[i][j] = __builtin_amdgcn_mfma_f32_16x16x32_f16(af[s][i], bf[s][j], acc[i][j], 0, 0, 0);
    asm volatile("s_waitcnt lgkmcnt(0)" ::: "memory");
    __builtin_amdgcn_s_barrier();
  }

  // epilogue: lane acc[i][j][r] = (m = mt*128+wm*64+i*16+kg*4+r, gate=j, unit=ug*32+wn*16+c0)
  const int dir = nt >> 2, ug = nt & 3;
  const int unit = ug * 32 + wn * 16 + c0;
  float bj[4];
#pragma unroll
  for (int j = 0; j < 4; ++j) bj[j] = bias[nt * 128 + wn * 64 + j * 16 + c0];
#pragma unroll
  for (int i = 0; i < 4; ++i)
#pragma unroll
    for (int r = 0; r < 4; ++r) {
      int m = mt * 128 + wm * 64 + i * 16 + kg * 4 + r;
      f16x4 v = { (f16)(acc[i][0][r] + bj[0]), (f16)(acc[i][1][r] + bj[1]),
                  (f16)(acc[i][2][r] + bj[2]), (f16)(acc[i][3][r] + bj[3]) };
      *(f16x4*)&xg[(size_t)m * 1024 + dir * 512 + unit * 4] = v;
    }
}

// ---------------- LSTM recurrence v3: 4-row groups, both dirs, dense 1-cell lanes ----------------
// block = 4 batch rows x both dirs; 8 waves: dir = w>>2, sp = w&3 (units sp*32..+32 as 2 sub-slices).
// Batch row j lives at MFMA M-row j*4 => C reg 0 of lane (c0,kg) is cell (row kg, unit c0) -- dense,
// no redistribution. hbuf double-buffered => ONE barrier per step.
template<int IS_L2>
__global__ __launch_bounds__(512, 1) void recur_kernel(
    const f16* __restrict__ xg, const f16* __restrict__ wf_base,
    f16* __restrict__ h1, float* __restrict__ pool, int b0)
{
  const int tid = threadIdx.x;
  const int w = tid >> 6, lane = tid & 63;
  const int dir = w >> 2, sp = w & 3;
  const int c0 = lane & 15, kg = lane >> 4;
  const int ci = blockIdx.x;

  __shared__ __align__(16) f16 hbuf[2][2][4][136];   // [dbuf][dir][row4][128+8 pad]

  f16x8 Wf[2][16];                                   // both sub-slices' W_hh B-frags (128 VGPR)
#pragma unroll
  for (int s = 0; s < 2; ++s) {
    const f16x8* wp = (const f16x8*)(wf_base + (size_t)((dir * 8 + sp * 2 + s) * 64 + lane) * 128);
#pragma unroll
    for (int f = 0; f < 16; ++f) Wf[s][f] = wp[f];
  }
  {
    f16* hb = &hbuf[0][0][0][0];
    for (int i = tid; i < 2 * 2 * 4 * 136; i += 512) hb[i] = (f16)0.f;
  }
  __syncthreads();

  const int u0 = sp * 32 + c0;
  const int u1 = u0 + 16;
  const size_t tokbase = (size_t)(ci * 4 + kg) * 256;
  const f16* xgu0 = xg + (size_t)dir * 512 + (size_t)u0 * 4;
  const f16* xgu1 = xg + (size_t)dir * 512 + (size_t)u1 * 4;
  f16* h1u0 = IS_L2 ? nullptr : h1 + (size_t)dir * 128 + u0;
  f16* h1u1 = IS_L2 ? nullptr : h1 + (size_t)dir * 128 + u1;

  float cst[2]  = {0.f, 0.f};
  float psum[2] = {0.f, 0.f};
  float pmax[2] = {-1e30f, -1e30f};

  f16x4 xa[2], xb[2];
  {
    const size_t m0 = (tokbase + (dir ? 255 : 0)) * 1024;
    xa[0] = *(const f16x4*)(xgu0 + m0);
    xa[1] = *(const f16x4*)(xgu1 + m0);
  }

  auto body = [&](int step, int p, f16x4* cur, f16x4* nxt) {
    const int t = dir ? (255 - step) : step;
    const int sn = (step < 255) ? step + 1 : 255;
    const int tn = dir ? (255 - sn) : sn;
    {
      const size_t mn = (tokbase + tn) * 1024;
      nxt[0] = *(const f16x4*)(xgu0 + mn);           // prefetch next step (reg dbuf)
      nxt[1] = *(const f16x4*)(xgu1 + mn);
    }

    f16x8 a[4];
#pragma unroll
    for (int q = 0; q < 4; ++q)
      a[q] = *(const f16x8*)&hbuf[p][dir][c0 >> 2][q * 32 + kg * 8];

    f32x4 acc[2][4] = {};
#pragma unroll
    for (int s = 0; s < 2; ++s)
#pragma unroll
      for (int g = 0; g < 4; ++g)
#pragma unroll
        for (int q = 0; q < 4; ++q)
          acc[s][g] = __builtin_amdgcn_mfma_f32_16x16x32_f16(a[q], Wf[s][g * 4 + q], acc[s][g], 0, 0, 0);

#pragma unroll
    for (int s = 0; s < 2; ++s) {
      float gi = acc[s][0][0] + (float)cur[s][0];
      float gf = acc[s][1][0] + (float)cur[s][1];
      float gG = acc[s][2][0] + (float)cur[s][2];
      float go = acc[s][3][0] + (float)cur[s][3];
      float si = sigm(gi), sf = sigm(gf), so = sigm(go);
      float cn = sf * cst[s] + si * tanh_(gG);
      cst[s] = cn;
      float hv = so * tanh_(cn);
      hbuf[p ^ 1][dir][kg][s ? u1 : u0] = (f16)hv;
      if constexpr (!IS_L2) {
        const size_t mo = (tokbase + t) * 256;
        *((s ? h1u1 : h1u0) + mo) = (f16)hv;
      } else {
        psum[s] += hv;
        pmax[s] = fmaxf(pmax[s], hv);
      }
    }
    asm volatile("s_waitcnt lgkmcnt(0)" ::: "memory");   // hbuf reads+writes done
    __builtin_amdgcn_s_barrier();                        // single barrier per step
  };

#pragma unroll 1
  for (int s2 = 0; s2 < 128; ++s2) {                     // manual 2x unroll: static reg dbuf
    body(2 * s2, 0, xa, xb);
    body(2 * s2 + 1, 1, xb, xa);
  }

  if constexpr (IS_L2) {
    const int b = b0 + ci * 4 + kg;
    pool[(size_t)b * 512 + dir * 128 + u0] = psum[0] * (1.f / 256.f);
    pool[(size_t)b * 512 + dir * 128 + u1] = psum[1] * (1.f / 256.f);
    pool[(size_t)b * 512 + 256 + dir * 128 + u0] = pmax[0];
    pool[(size_t)b * 512 + 256 + dir * 128 + u1] = pmax[1];
  }
}

// ---------------- head: dense(512x512)x2 + residual + out/aux projections ----------------
__global__ __launch_bounds__(256) void head_kernel(
    const float* __restrict__ pool,
    const float* __restrict__ w1t, const float* __restrict__ w2t,
    const float* __restrict__ b1, const float* __restrict__ b2,
    const float* __restrict__ wout, const float* __restrict__ bout,
    const float* __restrict__ waux, const float* __restrict__ baux,
    float* __restrict__ out)
{
  __shared__ float hc[4][512];
  __shared__ float hid[4][512];
  const int tid = threadIdx.x;
  const int rb = blockIdx.x * 4;
  for (int i = tid; i < 2048; i += 256) hc[i >> 9][i & 511] = pool[(size_t)rb * 512 + i];
  __syncthreads();

  float acc1[2][4] = {}, acc2[2][4] = {};
  for (int k = 0; k < 512; ++k) {
    float w1a = w1t[k * 512 + tid], w1b = w1t[k * 512 + tid + 256];
    float w2a = w2t[k * 512 + tid], w2b = w2t[k * 512 + tid + 256];
#pragma unroll
    for (int r = 0; r < 4; ++r) {
      float h = hc[r][k];
      acc1[0][r] += w1a * h; acc1[1][r] += w1b * h;
      acc2[0][r] += w2a * h; acc2[1][r] += w2b * h;
    }
  }
#pragma unroll
  for (int r = 0; r < 4; ++r) {
    hid[r][tid] = fmaxf(acc1[0][r] + b1[tid], 0.f) + hc[r][tid] + fmaxf(acc2[0][r] + b2[tid], 0.f);
    hid[r][tid + 256] = fmaxf(acc1[1][r] + b1[tid + 256], 0.f) + hc[r][tid + 256]
                      + fmaxf(acc2[1][r] + b2[tid + 256], 0.f);
  }
  __syncthreads();

  const int wv = tid >> 6, lane = tid & 63;
  for (int o = 0; o < 7; ++o) {
    const float* wrow = (o == 0) ? wout : (waux + (size_t)(o - 1) * 512);
    float s = 0.f;
#pragma unroll
    for (int m = 0; m < 8; ++m) s += hid[wv][lane + 64 * m] * wrow[lane + 64 * m];
#pragma unroll
    for (int off = 32; off >= 1; off >>= 1) s += __shfl_xor(s, off, 64);
    if (lane == 0) out[(size_t)(rb + wv) * 7 + o] = s + ((o == 0) ? bout[0] : baux[o - 1]);
  }
}

// ---------------- launcher ----------------
extern "C" void kernel_launch(void* const* d_in, const int* in_sizes, int n_in,
                              void* d_out, int out_size, void* d_ws, size_t ws_size,
                              hipStream_t stream) {
  const int*   x     = (const int*)d_in[0];
  const float* emb   = (const float*)d_in[1];
  const float* wih1f = (const float*)d_in[2];
  const float* whh1f = (const float*)d_in[3];
  const float* bih1f = (const float*)d_in[4];
  const float* bhh1f = (const float*)d_in[5];
  const float* wih1b = (const float*)d_in[6];
  const float* whh1b = (const float*)d_in[7];
  const float* bih1b = (const float*)d_in[8];
  const float* bhh1b = (const float*)d_in[9];
  const float* wih2f = (const float*)d_in[10];
  const float* whh2f = (const float*)d_in[11];
  const float* bih2f = (const float*)d_in[12];
  const float* bhh2f = (const float*)d_in[13];
  const float* wih2b = (const float*)d_in[14];
  const float* whh2b = (const float*)d_in[15];
  const float* bih2b = (const float*)d_in[16];
  const float* bhh2b = (const float*)d_in[17];
  const float* w1    = (const float*)d_in[18];
  const float* b1    = (const float*)d_in[19];
  const float* w2    = (const float*)d_in[20];
  const float* b2    = (const float*)d_in[21];
  const float* wout  = (const float*)d_in[22];
  const float* bout  = (const float*)d_in[23];
  const float* waux  = (const float*)d_in[24];
  const float* baux  = (const float*)d_in[25];

  char* ws = (char*)d_ws;
  f16* emb16 = (f16*)(ws + OFF_EMB16);
  f16* wih1p = (f16*)(ws + OFF_WIH1);
  f16* wih2p = (f16*)(ws + OFF_WIH2);
  f16* whhp  = (f16*)(ws + OFF_WHH);
  float* b1p = (float*)(ws + OFF_B1);
  float* b2p = (float*)(ws + OFF_B2);
  float* w1t = (float*)(ws + OFF_W1T);
  float* w2t = (float*)(ws + OFF_W2T);
  float* pool = (float*)(ws + OFF_POOL);

  // chunk factor G (pure function of ws_size -> identical sequence every call)
  int G = 1;
  while (G < 32 && OFF_H1 + (H1_FULL + XG_FULL) / (size_t)G > ws_size) G <<= 1;
  const int Bc = BATCH / G;                 // batch per chunk
  f16* h1c = (f16*)(ws + OFF_H1);
  f16* xgc = (f16*)(ws + OFF_H1 + H1_FULL / (size_t)G);

  prep_kernel<<<4096, 256, 0, stream>>>(emb,
      wih1f, whh1f, bih1f, bhh1f, wih1b, whh1b, bih1b, bhh1b,
      wih2f, whh2f, bih2f, bhh2f, wih2b, whh2b, bih2b, bhh2b,
      w1, w2, ws);

  for (int g = 0; g < G; ++g) {
    const int b0 = g * Bc;
    const int mt0 = b0 * 2;                 // 256 rows per batch elem = 2 M-tiles
    const int mtiles = Bc * 2;
    const int nb4 = Bc / 4;
    gemm_xg<5, true><<<mtiles * 8, 256, 0, stream>>>(emb16, x, wih1p, b1p, xgc, mt0);
    recur_kernel<0><<<nb4, 512, 0, stream>>>(xgc, whhp, h1c, nullptr, b0);
    gemm_xg<4, false><<<mtiles * 8, 256, 0, stream>>>(h1c, nullptr, wih2p, b2p, xgc, mt0);
    recur_kernel<1><<<nb4, 512, 0, stream>>>(xgc, whhp + 2 * 65536, nullptr, pool, b0);
  }

  head_kernel<<<128, 256, 0, stream>>>(pool, w1t, w2t, b1, b2, wout, bout, waux, baux,
                                       (float*)d_out);
}

// Round 5
// 749.397 us; speedup vs baseline: 2.8823x; 1.6802x over previous
//
#include <hip/hip_runtime.h>
#include <cstdint>
#include <cstddef>

typedef _Float16 f16;
typedef _Float16 f16x8 __attribute__((ext_vector_type(8)));
typedef _Float16 f16x4 __attribute__((ext_vector_type(4)));
typedef float f32x4 __attribute__((ext_vector_type(4)));

#define DEVI __device__ __forceinline__

// ---------------- problem sizes ----------------
constexpr int T_ = 256;
constexpr int BATCH = 512;
constexpr int M_ = BATCH * T_;   // 131072 tokens
constexpr int KE_ = 320;         // layer-1 K (300 padded to 320)
constexpr int K2_ = 256;         // layer-2 K

// ---------------- ws layout (bytes, 16B aligned) ----------------
constexpr size_t OFF_EMB16 = 0;                                     // [10000][320] f16
constexpr size_t OFF_WIH1  = OFF_EMB16 + (size_t)10000 * KE_ * 2;   // [1024][320] f16 (tile-permuted)
constexpr size_t OFF_WIH2  = OFF_WIH1 + (size_t)1024 * KE_ * 2;     // [1024][256] f16
constexpr size_t OFF_WHH   = OFF_WIH2 + (size_t)1024 * K2_ * 2;     // [4 ld][8w][64lane][16frag][8] f16
constexpr size_t OFF_B1    = OFF_WHH + (size_t)4 * 65536 * 2;       // [1024] f32 permuted bias
constexpr size_t OFF_B2    = OFF_B1 + 4096;                         // [1024] f32
constexpr size_t OFF_W1T   = OFF_B2 + 4096;                         // [512][512] f32 (transposed)
constexpr size_t OFF_W2T   = OFF_W1T + (size_t)512 * 512 * 4;
constexpr size_t OFF_POOL  = OFF_W2T + (size_t)512 * 512 * 4;       // [512][512] f32 (avg|max)
constexpr size_t OFF_XG1   = OFF_POOL + (size_t)512 * 512 * 4;      // [10240][1024] f16 token table (21MB)
constexpr size_t OFF_H1    = OFF_XG1 + (size_t)10240 * 1024 * 2;    // [131072][256] f16 (67MB)
constexpr size_t OFF_XG2   = OFF_H1 + (size_t)M_ * 256 * 2;         // [M_/G][1024] f16 chunk
constexpr size_t XG2_FULL  = (size_t)M_ * 1024 * 2;                 // 268MB full

DEVI void gload_lds16(const void* g, void* l) {
  __builtin_amdgcn_global_load_lds((const __attribute__((address_space(1))) void*)g,
                                   (__attribute__((address_space(3))) void*)l, 16, 0, 0);
}
DEVI float sigm(float x)  { return __builtin_amdgcn_rcpf(1.f + __expf(-x)); }
DEVI float tanh_(float x) { return 1.f - 2.f * __builtin_amdgcn_rcpf(1.f + __expf(2.f * x)); }

// xg col layout: col = dir*512 + unit*4 + gate   (gate contiguous, unit next)
// GEMM N-tile nt = dir*4 + ug; within tile r = wn*64 + j*16 + c0 -> gate=j, unit=ug*32+wn*16+c0
// B-perm row p = nt*128 + r -> orig W row = gate*128 + unit (per dir)
DEVI int borow(int p) {
  int r = p & 127;
  int ug = (p >> 7) & 3;
  int wn = r >> 6, j = (r >> 4) & 3, c0 = r & 15;
  return j * 128 + ug * 32 + wn * 16 + c0;
}

// ---------------- prep: fp16 conversion, permutation, fragment pre-arrangement ----------------
__global__ void prep_kernel(
    const float* __restrict__ emb,
    const float* __restrict__ wih1f, const float* __restrict__ whh1f,
    const float* __restrict__ bih1f, const float* __restrict__ bhh1f,
    const float* __restrict__ wih1b, const float* __restrict__ whh1b,
    const float* __restrict__ bih1b, const float* __restrict__ bhh1b,
    const float* __restrict__ wih2f, const float* __restrict__ whh2f,
    const float* __restrict__ bih2f, const float* __restrict__ bhh2f,
    const float* __restrict__ wih2b, const float* __restrict__ whh2b,
    const float* __restrict__ bih2b, const float* __restrict__ bhh2b,
    const float* __restrict__ w1, const float* __restrict__ w2,
    char* __restrict__ ws)
{
  f16* emb16   = (f16*)(ws + OFF_EMB16);
  f16* wih1p   = (f16*)(ws + OFF_WIH1);
  f16* wih2p   = (f16*)(ws + OFF_WIH2);
  f16* whhp    = (f16*)(ws + OFF_WHH);
  float* b1p   = (float*)(ws + OFF_B1);
  float* b2p   = (float*)(ws + OFF_B2);
  float* w1t   = (float*)(ws + OFF_W1T);
  float* w2t   = (float*)(ws + OFF_W2T);
  const int64_t stride = (int64_t)gridDim.x * blockDim.x;
  const int64_t t0 = (int64_t)blockIdx.x * blockDim.x + threadIdx.x;

  for (int64_t i = t0; i < (int64_t)10000 * 320; i += stride) {
    int r = (int)(i / 320), c = (int)(i % 320);
    emb16[i] = (c < 300) ? (f16)emb[r * 300 + c] : (f16)0.f;
  }
  for (int64_t i = t0; i < 1024 * 320; i += stride) {
    int p = (int)(i / 320), k = (int)(i % 320);
    int dir = p >> 9; int orig = borow(p & 511);
    const float* src = dir ? wih1b : wih1f;
    wih1p[i] = (k < 300) ? (f16)src[orig * 300 + k] : (f16)0.f;
  }
  for (int64_t i = t0; i < 1024 * 256; i += stride) {
    int p = (int)(i / 256), k = (int)(i % 256);
    int dir = p >> 9; int orig = borow(p & 511);
    const float* src = dir ? wih2b : wih2f;
    wih2p[i] = (f16)src[orig * 256 + k];
  }
  // W_hh recur B-frags: [(ld*8 + w)*64 + lane][frag f=g*4+kk][e]
  //   N-row = g*128 + w*16 + (lane&15);  k = kk*32 + (lane>>4)*8 + e
  for (int64_t i = t0; i < (int64_t)4 * 65536; i += stride) {
    int ld = (int)(i >> 16);              // layer*2 + dir
    int rem = (int)(i & 65535);
    int rec = rem >> 7;                    // w*64 + lane
    int w_ = rec >> 6, lane_ = rec & 63;
    int fe = rem & 127; int f_ = fe >> 3, e_ = fe & 7;
    int g_ = f_ >> 2, kk_ = f_ & 3;
    int n = g_ * 128 + w_ * 16 + (lane_ & 15);
    int k = kk_ * 32 + (lane_ >> 4) * 8 + e_;
    const float* src = (ld == 0) ? whh1f : (ld == 1) ? whh1b : (ld == 2) ? whh2f : whh2b;
    whhp[i] = (f16)src[n * 128 + k];
  }
  for (int64_t i = t0; i < 1024; i += stride) {
    int dir = (int)(i >> 9); int orig = borow((int)(i & 511));
    b1p[i] = dir ? (bih1b[orig] + bhh1b[orig]) : (bih1f[orig] + bhh1f[orig]);
    b2p[i] = dir ? (bih2b[orig] + bhh2b[orig]) : (bih2f[orig] + bhh2f[orig]);
  }
  for (int64_t i = t0; i < 512 * 512; i += stride) {
    int k = (int)(i >> 9), j = (int)(i & 511);
    w1t[i] = w1[j * 512 + k];
    w2t[i] = w2[j * 512 + k];
  }
}

// ---------------- input-gate GEMM: packed-layout xg, double-buffered LDS ----------------
// A rows linear (chunk-local / table rows). 128x128 tile, BK=64, 4 waves.
template<int KT>
__global__ __launch_bounds__(256, 2) void gemm_xg(
    const f16* __restrict__ Asrc, const f16* __restrict__ Bw,
    const float* __restrict__ bias, f16* __restrict__ xg)
{
  __shared__ __align__(16) f16 lA[2][8192];
  __shared__ __align__(16) f16 lB[2][8192];
  const int tid = threadIdx.x;
  const int w = tid >> 6, lane = tid & 63;
  const int mt = blockIdx.x >> 3, nt = blockIdx.x & 7;
  const int wm = w & 1, wn = w >> 1;
  const int l3 = lane >> 3, l7 = lane & 7;
  const int c0 = lane & 15, kg = lane >> 4;
  const int swz = l7 ^ l3;

  const f16* asrc[4];
  const f16* bsrc[4];
#pragma unroll
  for (int c = 0; c < 4; ++c) {
    int r = c * 32 + w * 8 + l3;
    asrc[c] = Asrc + (size_t)(mt * 128 + r) * (KT * 64) + swz * 8;
    bsrc[c] = Bw + (size_t)(nt * 128 + r) * (KT * 64) + swz * 8;
  }
  auto stage = [&](int kk, int d) {
#pragma unroll
    for (int c = 0; c < 4; ++c)
      gload_lds16(asrc[c] + kk * 64, &lA[d][(c * 256 + w * 64) * 8]);
#pragma unroll
    for (int c = 0; c < 4; ++c)
      gload_lds16(bsrc[c] + kk * 64, &lB[d][(c * 256 + w * 64) * 8]);
  };

  f32x4 acc[4][4] = {};
  stage(0, 0);
  for (int kk = 0; kk < KT; ++kk) {
    const int d = kk & 1;
    if (kk + 1 < KT) {
      stage(kk + 1, d ^ 1);
      asm volatile("s_waitcnt vmcnt(8)" ::: "memory");   // current tile landed, next in flight
    } else {
      asm volatile("s_waitcnt vmcnt(0)" ::: "memory");
    }
    __builtin_amdgcn_s_barrier();

    f16x8 af[2][4], bf[2][4];
#pragma unroll
    for (int s = 0; s < 2; ++s)
#pragma unroll
      for (int i = 0; i < 4; ++i) {
        int ra = wm * 64 + i * 16 + c0;
        int rb = wn * 64 + i * 16 + c0;
        int u = (s * 4 + kg) ^ l7;
        af[s][i] = *(const f16x8*)&lA[d][ra * 64 + u * 8];
        bf[s][i] = *(const f16x8*)&lB[d][rb * 64 + u * 8];
      }
#pragma unroll
    for (int s = 0; s < 2; ++s)
#pragma unroll
      for (int i = 0; i < 4; ++i)
#pragma unroll
        for (int j = 0; j < 4; ++j)
          acc[i][j] = __builtin_amdgcn_mfma_f32_16x16x32_f16(af[s][i], bf[s][j], acc[i][j], 0, 0, 0);
    asm volatile("s_waitcnt lgkmcnt(0)" ::: "memory");
    __builtin_amdgcn_s_barrier();
  }

  const int dir = nt >> 2, ug = nt & 3;
  const int unit = ug * 32 + wn * 16 + c0;
  float bj[4];
#pragma unroll
  for (int j = 0; j < 4; ++j) bj[j] = bias[nt * 128 + wn * 64 + j * 16 + c0];
#pragma unroll
  for (int i = 0; i < 4; ++i)
#pragma unroll
    for (int r = 0; r < 4; ++r) {
      int m = mt * 128 + wm * 64 + i * 16 + kg * 4 + r;
      f16x4 v = { (f16)(acc[i][0][r] + bj[0]), (f16)(acc[i][1][r] + bj[1]),
                  (f16)(acc[i][2][r] + bj[2]), (f16)(acc[i][3][r] + bj[3]) };
      *(f16x4*)&xg[(size_t)m * 1024 + dir * 512 + unit * 4] = v;
    }
}

// ---------------- LSTM recurrence v4: dir-per-block, 4 waves (one per SIMD) ----------------
// block = (dir, 4-batch group); wave sp owns units [sp*32, sp*32+32) as 2 sub-slices.
// L1 (!IS_L2): xg = token table [10240][1024], gathered by token id (LLC-resident).
// hbuf row stride 144 f16 = 72 dwords == 8 mod 32 -> A-reads exactly 2-way (free).
template<int IS_L2>
__global__ __launch_bounds__(256, 2) void recur_kernel(
    const f16* __restrict__ xg, const int* __restrict__ xtok,
    const f16* __restrict__ whh2, f16* __restrict__ h1,
    float* __restrict__ pool, int b0, int nblk)
{
  const int tid = threadIdx.x;
  const int sp = tid >> 6, lane = tid & 63;
  const int dir = blockIdx.x / nblk, ci = blockIdx.x % nblk;
  const int c0 = lane & 15, kg = lane >> 4;

  __shared__ __align__(16) f16 hbuf[2][4][144];

  f16x8 Wf[2][16];                                   // 128 VGPR of W_hh B-frags
#pragma unroll
  for (int s = 0; s < 2; ++s) {
    const f16x8* wp = (const f16x8*)(whh2 + (size_t)dir * 65536 +
                                     (size_t)((sp * 2 + s) * 64 + lane) * 128);
#pragma unroll
    for (int f = 0; f < 16; ++f) Wf[s][f] = wp[f];
  }
  for (int i = tid; i < 2 * 4 * 144; i += 256) (&hbuf[0][0][0])[i] = (f16)0.f;
  __syncthreads();

  const int u0 = sp * 32 + c0, u1 = u0 + 16;
  const int brow = ci * 4 + kg;                      // chunk-local batch row
  const int gb = b0 + brow;                          // global batch row
  const f16* xgu0 = xg + dir * 512 + u0 * 4;
  const f16* xgu1 = xg + dir * 512 + u1 * 4;
  const int* xr = nullptr;
  if constexpr (!IS_L2) xr = xtok + (size_t)gb * 256;

  auto tAt = [&](int step) { int s = step < 256 ? step : 255; return dir ? 255 - s : s; };

  float cst[2] = {0.f, 0.f}, psum[2] = {0.f, 0.f}, pmax[2] = {-1e30f, -1e30f};

  f16x4 xa[2], xb[2];
  int tok1 = 0;
  if constexpr (!IS_L2) {
    const int tok0 = xr[tAt(0)];
    xa[0] = *(const f16x4*)(xgu0 + (size_t)tok0 * 1024);
    xa[1] = *(const f16x4*)(xgu1 + (size_t)tok0 * 1024);
    tok1 = xr[tAt(1)];
  } else {
    const size_t m0 = ((size_t)brow * 256 + tAt(0)) * 1024;
    xa[0] = *(const f16x4*)(xgu0 + m0);
    xa[1] = *(const f16x4*)(xgu1 + m0);
  }

  auto body = [&](int step, int p, f16x4* cur, f16x4* nxt) {
    const int t = tAt(step);
    if constexpr (!IS_L2) {
      const size_t mn = (size_t)tok1 * 1024;          // token loaded last iter
      nxt[0] = *(const f16x4*)(xgu0 + mn);
      nxt[1] = *(const f16x4*)(xgu1 + mn);
      tok1 = xr[tAt(step + 2)];                       // token for step+2
    } else {
      const size_t mn = ((size_t)brow * 256 + tAt(step + 1)) * 1024;
      nxt[0] = *(const f16x4*)(xgu0 + mn);
      nxt[1] = *(const f16x4*)(xgu1 + mn);
    }

    f16x8 a[4];
#pragma unroll
    for (int q = 0; q < 4; ++q)
      a[q] = *(const f16x8*)&hbuf[p][c0 >> 2][q * 32 + kg * 8];

    f32x4 acc[2][4] = {};
#pragma unroll
    for (int s = 0; s < 2; ++s)
#pragma unroll
      for (int g = 0; g < 4; ++g)
#pragma unroll
        for (int q = 0; q < 4; ++q)
          acc[s][g] = __builtin_amdgcn_mfma_f32_16x16x32_f16(a[q], Wf[s][g * 4 + q], acc[s][g], 0, 0, 0);

#pragma unroll
    for (int s = 0; s < 2; ++s) {
      const float gi = acc[s][0][0] + (float)cur[s][0];
      const float gf = acc[s][1][0] + (float)cur[s][1];
      const float gG = acc[s][2][0] + (float)cur[s][2];
      const float go = acc[s][3][0] + (float)cur[s][3];
      const float si = sigm(gi), sf = sigm(gf), so = sigm(go);
      const float cn = sf * cst[s] + si * tanh_(gG);
      cst[s] = cn;
      const float hv = so * tanh_(cn);
      hbuf[p ^ 1][kg][s ? u1 : u0] = (f16)hv;
      if constexpr (!IS_L2) {
        h1[((size_t)gb * 256 + t) * 256 + dir * 128 + (s ? u1 : u0)] = (f16)hv;
      } else {
        psum[s] += hv;
        pmax[s] = fmaxf(pmax[s], hv);
      }
    }
    asm volatile("s_waitcnt lgkmcnt(0)" ::: "memory"); // hbuf reads+writes done
    __builtin_amdgcn_s_barrier();                      // single barrier per step
  };

#pragma unroll 1
  for (int s2 = 0; s2 < 128; ++s2) {                   // static reg double-buffer
    body(2 * s2, 0, xa, xb);
    body(2 * s2 + 1, 1, xb, xa);
  }

  if constexpr (IS_L2) {
    pool[(size_t)gb * 512 + dir * 128 + u0] = psum[0] * (1.f / 256.f);
    pool[(size_t)gb * 512 + dir * 128 + u1] = psum[1] * (1.f / 256.f);
    pool[(size_t)gb * 512 + 256 + dir * 128 + u0] = pmax[0];
    pool[(size_t)gb * 512 + 256 + dir * 128 + u1] = pmax[1];
  }
}

// ---------------- head: dense(512x512)x2 + residual + out/aux projections ----------------
__global__ __launch_bounds__(256) void head_kernel(
    const float* __restrict__ pool,
    const float* __restrict__ w1t, const float* __restrict__ w2t,
    const float* __restrict__ b1, const float* __restrict__ b2,
    const float* __restrict__ wout, const float* __restrict__ bout,
    const float* __restrict__ waux, const float* __restrict__ baux,
    float* __restrict__ out)
{
  __shared__ float hc[4][512];
  __shared__ float hid[4][512];
  const int tid = threadIdx.x;
  const int rb = blockIdx.x * 4;
  for (int i = tid; i < 2048; i += 256) hc[i >> 9][i & 511] = pool[(size_t)rb * 512 + i];
  __syncthreads();

  float acc1[2][4] = {}, acc2[2][4] = {};
  for (int k = 0; k < 512; ++k) {
    float w1a = w1t[k * 512 + tid], w1b = w1t[k * 512 + tid + 256];
    float w2a = w2t[k * 512 + tid], w2b = w2t[k * 512 + tid + 256];
#pragma unroll
    for (int r = 0; r < 4; ++r) {
      float h = hc[r][k];
      acc1[0][r] += w1a * h; acc1[1][r] += w1b * h;
      acc2[0][r] += w2a * h; acc2[1][r] += w2b * h;
    }
  }
#pragma unroll
  for (int r = 0; r < 4; ++r) {
    hid[r][tid] = fmaxf(acc1[0][r] + b1[tid], 0.f) + hc[r][tid] + fmaxf(acc2[0][r] + b2[tid], 0.f);
    hid[r][tid + 256] = fmaxf(acc1[1][r] + b1[tid + 256], 0.f) + hc[r][tid + 256]
                      + fmaxf(acc2[1][r] + b2[tid + 256], 0.f);
  }
  __syncthreads();

  const int wv = tid >> 6, lane = tid & 63;
  for (int o = 0; o < 7; ++o) {
    const float* wrow = (o == 0) ? wout : (waux + (size_t)(o - 1) * 512);
    float s = 0.f;
#pragma unroll
    for (int m = 0; m < 8; ++m) s += hid[wv][lane + 64 * m] * wrow[lane + 64 * m];
#pragma unroll
    for (int off = 32; off >= 1; off >>= 1) s += __shfl_xor(s, off, 64);
    if (lane == 0) out[(size_t)(rb + wv) * 7 + o] = s + ((o == 0) ? bout[0] : baux[o - 1]);
  }
}

// ---------------- launcher ----------------
extern "C" void kernel_launch(void* const* d_in, const int* in_sizes, int n_in,
                              void* d_out, int out_size, void* d_ws, size_t ws_size,
                              hipStream_t stream) {
  const int*   x     = (const int*)d_in[0];
  const float* emb   = (const float*)d_in[1];
  const float* wih1f = (const float*)d_in[2];
  const float* whh1f = (const float*)d_in[3];
  const float* bih1f = (const float*)d_in[4];
  const float* bhh1f = (const float*)d_in[5];
  const float* wih1b = (const float*)d_in[6];
  const float* whh1b = (const float*)d_in[7];
  const float* bih1b = (const float*)d_in[8];
  const float* bhh1b = (const float*)d_in[9];
  const float* wih2f = (const float*)d_in[10];
  const float* whh2f = (const float*)d_in[11];
  const float* bih2f = (const float*)d_in[12];
  const float* bhh2f = (const float*)d_in[13];
  const float* wih2b = (const float*)d_in[14];
  const float* whh2b = (const float*)d_in[15];
  const float* bih2b = (const float*)d_in[16];
  const float* bhh2b = (const float*)d_in[17];
  const float* w1    = (const float*)d_in[18];
  const float* b1    = (const float*)d_in[19];
  const float* w2    = (const float*)d_in[20];
  const float* b2    = (const float*)d_in[21];
  const float* wout  = (const float*)d_in[22];
  const float* bout  = (const float*)d_in[23];
  const float* waux  = (const float*)d_in[24];
  const float* baux  = (const float*)d_in[25];

  char* ws = (char*)d_ws;
  f16* emb16 = (f16*)(ws + OFF_EMB16);
  f16* wih1p = (f16*)(ws + OFF_WIH1);
  f16* wih2p = (f16*)(ws + OFF_WIH2);
  f16* whhp  = (f16*)(ws + OFF_WHH);
  float* b1p = (float*)(ws + OFF_B1);
  float* b2p = (float*)(ws + OFF_B2);
  float* w1t = (float*)(ws + OFF_W1T);
  float* w2t = (float*)(ws + OFF_W2T);
  float* pool = (float*)(ws + OFF_POOL);
  f16* xg1t  = (f16*)(ws + OFF_XG1);
  f16* h1f   = (f16*)(ws + OFF_H1);
  f16* xg2c  = (f16*)(ws + OFF_XG2);

  // chunk factor G for the layer-2 xg buffer only (pure function of ws_size)
  int G = 1;
  while (G < 32 && OFF_XG2 + XG2_FULL / (size_t)G > ws_size) G <<= 1;
  const int Bc = BATCH / G;

  prep_kernel<<<4096, 256, 0, stream>>>(emb,
      wih1f, whh1f, bih1f, bhh1f, wih1b, whh1b, bih1b, bhh1b,
      wih2f, whh2f, bih2f, bhh2f, wih2b, whh2b, bih2b, bhh2b,
      w1, w2, ws);

  // layer-1 gate table over the 10000-token vocabulary (80 M-tiles of 128)
  gemm_xg<5><<<80 * 8, 256, 0, stream>>>(emb16, wih1p, b1p, xg1t);

  // layer-1 recurrence: full batch, one dispatch, 256 blocks
  recur_kernel<0><<<2 * 128, 256, 0, stream>>>(xg1t, x, whhp, h1f, nullptr, 0, 128);

  // layer-2: chunked input GEMM + recurrence
  for (int g = 0; g < G; ++g) {
    const int b0 = g * Bc;
    gemm_xg<4><<<(Bc * 2) * 8, 256, 0, stream>>>(h1f + (size_t)b0 * 65536, wih2p, b2p, xg2c);
    recur_kernel<1><<<2 * (Bc / 4), 256, 0, stream>>>(xg2c, nullptr, whhp + 2 * 65536,
                                                      nullptr, pool, b0, Bc / 4);
  }

  head_kernel<<<128, 256, 0, stream>>>(pool, w1t, w2t, b1, b2, wout, bout, waux, baux,
                                       (float*)d_out);
}